// Round 4
// baseline (600.556 us; speedup 1.0000x reference)
//
#include <hip/hip_runtime.h>
#include <math.h>

typedef __bf16 bf16;
typedef __bf16 bf16x8 __attribute__((ext_vector_type(8)));
typedef float f32x4 __attribute__((ext_vector_type(4)));

constexpr int cT = 2048;
constexpr int cD = 4096;
constexpr int cH = 32;
constexpr int cKV = 8;
constexpr int cHD = 128;
constexpr float SCALE = 0.08838834764831845f; // 1/sqrt(128)

// Async global->LDS, 16B per lane. LDS dest must be WAVE-UNIFORM base;
// lane i's data lands at base + i*16 (guide §5 caveat).
__device__ __forceinline__ void gl_lds16(const bf16* g, bf16* l) {
  __builtin_amdgcn_global_load_lds(
      (const __attribute__((address_space(1))) unsigned*)g,
      (__attribute__((address_space(3))) unsigned*)l, 16, 0, 0);
}

// Counted vmcnt wait (T4). Immediate must be a literal in the asm string.
template <int N>
__device__ __forceinline__ void wait_vmcnt() {
  if constexpr (N == 0) asm volatile("s_waitcnt vmcnt(0)" ::: "memory");
  else if constexpr (N == 3) asm volatile("s_waitcnt vmcnt(3)" ::: "memory");
  else if constexpr (N == 4) asm volatile("s_waitcnt vmcnt(4)" ::: "memory");
  else if constexpr (N == 6) asm volatile("s_waitcnt vmcnt(6)" ::: "memory");
  else if constexpr (N == 8) asm volatile("s_waitcnt vmcnt(8)" ::: "memory");
  else static_assert(N == 0, "unsupported vmcnt literal");
}

__device__ inline bf16x8 load8_cvt(const float* __restrict__ p) {
  float4 a = *(const float4*)p;
  float4 b = *(const float4*)(p + 4);
  bf16x8 r;
  r[0] = (bf16)a.x; r[1] = (bf16)a.y; r[2] = (bf16)a.z; r[3] = (bf16)a.w;
  r[4] = (bf16)b.x; r[5] = (bf16)b.y; r[6] = (bf16)b.z; r[7] = (bf16)b.w;
  return r;
}

// ---------------------------------------------------------------------------
// fp32 -> bf16 elementwise (8 elems/thread)
// ---------------------------------------------------------------------------
__global__ __launch_bounds__(256) void convert_kernel(const float* __restrict__ s,
                                                      bf16* __restrict__ d) {
  const size_t i = (size_t)(blockIdx.x * 256 + threadIdx.x) * 8;
  *(bf16x8*)(d + i) = load8_cvt(s + i);
}

// ---------------------------------------------------------------------------
// Transpose + convert: dst[c][r] = (bf16)src[r][c]. src is R x C fp32,
// dst is C x R bf16 (row stride R). 64x64 LDS tile.
// ---------------------------------------------------------------------------
__global__ __launch_bounds__(256) void convT_kernel(const float* __restrict__ src,
                                                    bf16* __restrict__ dst,
                                                    int R, int C) {
  __shared__ float t[64][65];
  const int r0 = blockIdx.y * 64, c0 = blockIdx.x * 64;
  const int tid = threadIdx.x;
  {
    const int lr = tid >> 4, lc = (tid & 15) * 4;
#pragma unroll
    for (int i = 0; i < 4; ++i) {
      float4 v4 = *(const float4*)(src + (size_t)(r0 + lr + i * 16) * C + c0 + lc);
      t[lr + i * 16][lc] = v4.x;
      t[lr + i * 16][lc + 1] = v4.y;
      t[lr + i * 16][lc + 2] = v4.z;
      t[lr + i * 16][lc + 3] = v4.w;
    }
  }
  __syncthreads();
  {
    const int c = tid >> 2, rb = (tid & 3) * 16;
#pragma unroll
    for (int half = 0; half < 2; ++half) {
      bf16x8 o;
#pragma unroll
      for (int j = 0; j < 8; ++j) o[j] = (bf16)t[rb + half * 8 + j][c];
      *(bf16x8*)(dst + (size_t)(c0 + c) * R + r0 + rb + half * 8) = o;
    }
  }
}

// ---------------------------------------------------------------------------
// m97-structure GEMM + T3/T4 counted-vmcnt pipeline:
// C[M,N] = A[M,K] * BT[N,K]^T, both operands bf16 K-major. 128xBN block
// tile, BK=32 slices, 256 threads (4 waves, 2x2).
//
// 4-slot LDS ring of K-slices, prefetch depth 3, ONE raw s_barrier per
// slice, and COUNTED vmcnt (never 0 in the main loop). Per slice s:
//   s_waitcnt vmcnt(2*LPS)   -- own slice-s loads landed; s+1,s+2 in flight
//   s_barrier                -- all waves' slice-s data now in LDS
//   issue gl_lds slice s+3 into ring[(s+3)&3]   (slot last read at s-1)
//   ds_read + 16 MFMA on slice s
// Rationale: at this shape the grid gives 2 blocks/CU; __syncthreads()'
// implicit vmcnt(0) drained to the NEWEST prefetch load, exposing HBM/L2
// latency every slice (MfmaUtil 28%). Counted waits target only the oldest
// slice (T4, m218: +38% at 4k). Race-safety: slot (s+3)&3's readers (slice
// s-1) finished before barrier_s (ds_reads consumed before their MFMAs,
// which precede the barrier in program order); each wave waits for its own
// slice-s loads before barrier_s, so the barrier publishes slice s globally.
// Tail peels 3 iterations with vmcnt(2*LPS / LPS / 0).
// ---------------------------------------------------------------------------
template <int BN, typename OutT>
__global__ __launch_bounds__(256) void gemm_bt_kernel(const bf16* __restrict__ A,
                                                      const bf16* __restrict__ BT,
                                                      OutT* __restrict__ C,
                                                      int M, int N, int K) {
  __shared__ __align__(16) bf16 As[4][128][32];
  __shared__ __align__(16) bf16 Bs[4][BN][32];
  constexpr int TN = BN / 32;       // n-tiles per wave
  constexpr int LPS = 2 + BN / 64;  // gl_lds per wave per slice

  const int tid = threadIdx.x;
  const int lane = tid & 63, w = tid >> 6;
  const int ln = lane & 15, kg = lane >> 4;
  const int m0 = blockIdx.y * 128, n0 = blockIdx.x * BN;
  const int wm = (w >> 1) * 64;
  const int wn = (w & 1) * (BN / 2);

  f32x4 acc[4][TN] = {};

  const int srow = lane >> 2;          // 0..15 within a 16-row chunk
  const int schk = (lane & 3) * 8;     // k-chunk (bf16 elems)
  const bf16* aG = A + (size_t)(m0 + srow) * K + schk;
  const bf16* bG = BT + (size_t)(n0 + srow) * K + schk;

  auto stage = [&](int slice) {
    const int sb = slice & 3;
    const int kt = slice * 32;
#pragma unroll
    for (int j = 0; j < 2; ++j)
      gl_lds16(aG + (size_t)(w * 32 + j * 16) * K + kt, &As[sb][w * 32 + j * 16][0]);
#pragma unroll
    for (int j = 0; j < BN / 64; ++j)
      gl_lds16(bG + (size_t)(w * (BN / 4) + j * 16) * K + kt,
               &Bs[sb][w * (BN / 4) + j * 16][0]);
  };

  auto compute = [&](int slice) {
    const int sb = slice & 3;
    bf16x8 af[4], bfr[TN];
#pragma unroll
    for (int tm = 0; tm < 4; ++tm)
      af[tm] = *(const bf16x8*)(&As[sb][wm + tm * 16 + ln][kg * 8]);
#pragma unroll
    for (int tn = 0; tn < TN; ++tn)
      bfr[tn] = *(const bf16x8*)(&Bs[sb][wn + tn * 16 + ln][kg * 8]);
#pragma unroll
    for (int tm = 0; tm < 4; ++tm)
#pragma unroll
      for (int tn = 0; tn < TN; ++tn)
        acc[tm][tn] = __builtin_amdgcn_mfma_f32_16x16x32_bf16(
            af[tm], bfr[tn], acc[tm][tn], 0, 0, 0);
  };

  const int NS = K / 32;  // 128 slices for K=4096

  stage(0);
  stage(1);
  stage(2);

  for (int s = 0; s < NS - 3; ++s) {
    wait_vmcnt<2 * LPS>();
    __builtin_amdgcn_s_barrier();
    stage(s + 3);
    compute(s);
  }
  wait_vmcnt<2 * LPS>();
  __builtin_amdgcn_s_barrier();
  compute(NS - 3);
  wait_vmcnt<LPS>();
  __builtin_amdgcn_s_barrier();
  compute(NS - 2);
  wait_vmcnt<0>();
  __builtin_amdgcn_s_barrier();
  compute(NS - 1);

#pragma unroll
  for (int tm = 0; tm < 4; ++tm)
#pragma unroll
    for (int tn = 0; tn < TN; ++tn)
#pragma unroll
      for (int r = 0; r < 4; ++r)
        C[(size_t)(m0 + wm + tm * 16 + kg * 4 + r) * N + n0 + wn + tn * 16 + ln] =
            (OutT)acc[tm][tn][r];
}

// ---------------------------------------------------------------------------
// RMSNorm (per head, HD=128) + RoPE, in place on bf16 q and kv(k part).
// Q additionally pre-scaled by 1/sqrt(HD). One wave per (t, head).
// ---------------------------------------------------------------------------
__global__ __launch_bounds__(256) void norm_rope_kernel(bf16* __restrict__ q,
                                                        bf16* __restrict__ kv,
                                                        const float* __restrict__ qw,
                                                        const float* __restrict__ kw) {
  const int gw = (blockIdx.x * 256 + threadIdx.x) >> 6;
  const int lane = threadIdx.x & 63;
  bf16* base;
  const float* wgt;
  float post;
  int t;
  if (gw < cT * cH) {
    t = gw >> 5;
    int h = gw & 31;
    base = q + (size_t)t * (cH * cHD) + h * cHD;
    wgt = qw;
    post = SCALE;
  } else {
    int g2 = gw - cT * cH;
    t = g2 >> 3;
    int h = g2 & 7;
    base = kv + (size_t)t * (2 * cKV * cHD) + h * cHD;  // k part of kv buffer
    wgt = kw;
    post = 1.0f;
  }
  const int d0 = lane * 2;
  float x0 = (float)base[d0], x1 = (float)base[d0 + 1];
  float ss = x0 * x0 + x1 * x1;
#pragma unroll
  for (int off = 32; off > 0; off >>= 1) ss += __shfl_xor(ss, off, 64);
  const float rs = rsqrtf(ss * (1.0f / 128.0f) + 1e-6f);
  float y0 = x0 * rs * wgt[d0];
  float y1 = x1 * rs * wgt[d0 + 1];
  float p0 = __shfl_xor(y0, 32, 64);
  float p1 = __shfl_xor(y1, 32, 64);
  const float sgn = (lane < 32) ? -1.0f : 1.0f;  // first half gets -x2
  const int fi = d0 & 63;
  const float c1 = -19.93156856932417f / 64.0f;  // -log2(1e6)/64
  float inv0 = exp2f((float)fi * c1);
  float inv1 = exp2f((float)(fi + 1) * c1);
  float a0 = (float)t * inv0, a1 = (float)t * inv1;
  float o0 = (y0 * cosf(a0) + sgn * p0 * sinf(a0)) * post;
  float o1 = (y1 * cosf(a1) + sgn * p1 * sinf(a1)) * post;
  base[d0] = (bf16)o0;
  base[d0 + 1] = (bf16)o1;
}

// ---------------------------------------------------------------------------
// Score upper bound: S <= 128*SCALE*max|qw|*max|kw| (RMSNorm bounds row norms,
// RoPE is a rotation). Used as the fixed softmax shift C (shift-invariant).
// ---------------------------------------------------------------------------
__global__ void bound_kernel(const float* __restrict__ qw,
                             const float* __restrict__ kw,
                             float* __restrict__ cb) {
  const int lane = threadIdx.x;  // 64 threads
  float mq = fmaxf(fabsf(qw[lane]), fabsf(qw[lane + 64]));
  float mk = fmaxf(fabsf(kw[lane]), fabsf(kw[lane + 64]));
#pragma unroll
  for (int off = 32; off > 0; off >>= 1) {
    mq = fmaxf(mq, __shfl_xor(mq, off, 64));
    mk = fmaxf(mk, __shfl_xor(mk, off, 64));
  }
  if (lane == 0) *cb = 128.0f * SCALE * mq * mk + 1e-3f;
}

// ---------------------------------------------------------------------------
// MFMA flash attention (causal, GQA), fixed-C softmax (no per-tile cross-lane
// reductions, no rescaling). 128 Q rows per block, 4 waves, wave = 32 rows.
// Each Ks/VT B-frag read feeds 2 MFMAs (mt=0,1).
//
// Scheduling: LDS = 54272 B and grid = 512 -> exactly 2 resident blocks/CU,
// co-resident pair = (linear i, i+256) = same blockIdx.x. Map qt so the pair
// is work-complementary: every CU totals 36 tile-units (was 4..64 -> tail).
//
// Staging: T14 async split. K/V tile kt+1 global loads are issued right after
// the first barrier and land while tile kt computes; regs are written to LDS
// at the top of the next iteration (after the trailing barrier).
// ---------------------------------------------------------------------------
__global__ __launch_bounds__(256) void flash_kernel(const bf16* __restrict__ q,
                                                    const bf16* __restrict__ kv,
                                                    const float* __restrict__ cb,
                                                    bf16* __restrict__ out) {
  __shared__ bf16 Ks[64][136];
  __shared__ bf16 VT[128][72];
  __shared__ bf16 Ps[4][32][72];

  constexpr int KVS = 2 * cKV * cHD;  // 2048, kv row stride
  // Balanced complementary mapping (see header comment): covers every (qt,h)
  // exactly once: y<16 -> qt=15-x with h=y; y>=16 -> qt=x with h=y.
  const int qt = (blockIdx.y < 16) ? (15 - blockIdx.x) : blockIdx.x;
  const int h = blockIdx.y;
  const int qm0 = qt * 128;
  const int kh = h >> 2;  // kv head (G=4)
  const int tid = threadIdx.x;
  const int lane = tid & 63, w = tid >> 6;
  const int ln = lane & 15, kg = lane >> 4;
  const float C = *cb;
  const int row0 = qm0 + w * 32;  // wave's first Q row

  // --- preload Q A-frags: rows row0 + mt*16 + ln ---
  bf16x8 qa[2][4];
#pragma unroll
  for (int mt = 0; mt < 2; ++mt) {
    const bf16* qrow =
        q + (size_t)(row0 + mt * 16 + ln) * (cH * cHD) + h * cHD + kg * 8;
#pragma unroll
    for (int kk = 0; kk < 4; ++kk) qa[mt][kk] = *(const bf16x8*)(qrow + kk * 32);
  }

  const int sl = tid >> 2, sc = tid & 3;    // K staging: row sl, chunk sc*32
  const int vp = tid & 31, vc = tid >> 5;   // V staging: row-pair 2vp, chunk vc*16
  const bf16* kbase = kv + (size_t)sl * KVS + kh * cHD + sc * 32;
  const bf16* vbase = kv + cKV * cHD + (size_t)(2 * vp) * KVS + kh * cHD + vc * 16;

  float l_r[2][4] = {};
  f32x4 o_acc[2][8] = {};

  const int nkt = 2 * qt + 2;

  // ---- prologue: load tile 0 into staging regs ----
  bf16x8 kr[4], vr[4];
#pragma unroll
  for (int i = 0; i < 4; ++i) kr[i] = *(const bf16x8*)(kbase + i * 8);
  vr[0] = *(const bf16x8*)(vbase);
  vr[1] = *(const bf16x8*)(vbase + 8);
  vr[2] = *(const bf16x8*)(vbase + KVS);
  vr[3] = *(const bf16x8*)(vbase + KVS + 8);

  for (int kt = 0; kt < nkt; ++kt) {
    // ---- write staged K tile (loaded last iter / prologue) ----
#pragma unroll
    for (int i = 0; i < 4; ++i)
      *(bf16x8*)(&Ks[sl][sc * 32 + i * 8]) = kr[i];
    // ---- write staged V tile transposed (pair-packed b32 writes) ----
#pragma unroll
    for (int i = 0; i < 8; ++i) {
      union { bf16 hh[2]; unsigned u; } pk;
      pk.hh[0] = vr[0][i]; pk.hh[1] = vr[2][i];
      *(unsigned*)(&VT[vc * 16 + i][2 * vp]) = pk.u;
      pk.hh[0] = vr[1][i]; pk.hh[1] = vr[3][i];
      *(unsigned*)(&VT[vc * 16 + 8 + i][2 * vp]) = pk.u;
    }
    __syncthreads();

    // ---- issue next-tile global loads; they land under the compute below ----
    if (kt + 1 < nkt) {
      const bf16* kn = kbase + (size_t)(kt + 1) * 64 * KVS;
      const bf16* vn = vbase + (size_t)(kt + 1) * 64 * KVS;
#pragma unroll
      for (int i = 0; i < 4; ++i) kr[i] = *(const bf16x8*)(kn + i * 8);
      vr[0] = *(const bf16x8*)(vn);
      vr[1] = *(const bf16x8*)(vn + 8);
      vr[2] = *(const bf16x8*)(vn + KVS);
      vr[3] = *(const bf16x8*)(vn + KVS + 8);
    }

    // ---- S = Q K^T : B-frags shared across mt ----
    f32x4 s_acc[2][4] = {};
    __builtin_amdgcn_s_setprio(1);
#pragma unroll
    for (int kk = 0; kk < 4; ++kk)
#pragma unroll
      for (int nt = 0; nt < 4; ++nt) {
        bf16x8 bfr = *(const bf16x8*)(&Ks[nt * 16 + ln][kk * 32 + kg * 8]);
        s_acc[0][nt] = __builtin_amdgcn_mfma_f32_16x16x32_bf16(
            qa[0][kk], bfr, s_acc[0][nt], 0, 0, 0);
        s_acc[1][nt] = __builtin_amdgcn_mfma_f32_16x16x32_bf16(
            qa[1][kk], bfr, s_acc[1][nt], 0, 0, 0);
      }
    __builtin_amdgcn_s_setprio(0);

    // ---- P = exp(S - C) (masked on edge tiles), per-lane row sums ----
    const bool edge = (kt * 64 + 63 > row0);  // wave-uniform
#pragma unroll
    for (int mt = 0; mt < 2; ++mt)
#pragma unroll
      for (int nt = 0; nt < 4; ++nt)
#pragma unroll
        for (int r = 0; r < 4; ++r) {
          float pe = __expf(s_acc[mt][nt][r] - C);
          if (edge) {
            int col = kt * 64 + nt * 16 + ln;
            int row = row0 + mt * 16 + kg * 4 + r;
            if (col > row) pe = 0.f;
          }
          l_r[mt][r] += pe;
          Ps[w][mt * 16 + kg * 4 + r][nt * 16 + ln] = (bf16)pe;
        }

    // ---- O += P V (no rescale needed with fixed C) ----
    __builtin_amdgcn_s_setprio(1);
#pragma unroll
    for (int kk2 = 0; kk2 < 2; ++kk2) {
      bf16x8 pa0 = *(const bf16x8*)(&Ps[w][ln][kk2 * 32 + kg * 8]);
      bf16x8 pa1 = *(const bf16x8*)(&Ps[w][16 + ln][kk2 * 32 + kg * 8]);
#pragma unroll
      for (int dt = 0; dt < 8; ++dt) {
        bf16x8 vb = *(const bf16x8*)(&VT[dt * 16 + ln][kk2 * 32 + kg * 8]);
        o_acc[0][dt] = __builtin_amdgcn_mfma_f32_16x16x32_bf16(
            pa0, vb, o_acc[0][dt], 0, 0, 0);
        o_acc[1][dt] = __builtin_amdgcn_mfma_f32_16x16x32_bf16(
            pa1, vb, o_acc[1][dt], 0, 0, 0);
      }
    }
    __builtin_amdgcn_s_setprio(0);
    __syncthreads();
  }

  // ---- one final cross-lane reduction of l over ln (within kg group) ----
#pragma unroll
  for (int mt = 0; mt < 2; ++mt)
#pragma unroll
    for (int r = 0; r < 4; ++r) {
      float l = l_r[mt][r];
#pragma unroll
      for (int off = 1; off <= 8; off <<= 1) l += __shfl_xor(l, off, 64);
      l_r[mt][r] = 1.0f / l;
    }

  // ---- epilogue ----
#pragma unroll
  for (int mt = 0; mt < 2; ++mt) {
    bf16* op = out + (size_t)(row0 + mt * 16 + kg * 4) * (cH * cHD) + h * cHD + ln;
#pragma unroll
    for (int dt = 0; dt < 8; ++dt)
#pragma unroll
      for (int r = 0; r < 4; ++r)
        op[(size_t)r * (cH * cHD) + dt * 16] = (bf16)(o_acc[mt][dt][r] * l_r[mt][r]);
  }
}

// ---------------------------------------------------------------------------
// Workspace choreography (peak exactly 64 MiB, stream-ordered reuse):
//   [ 0,16M): xb (x bf16)            -> attn (after flash)
//   [16,48M): WqT (32M)              -> { WkvT [16,32M), kv [32,40M), Cb@46M }
//                                    -> WoT (after flash)
//   [48,64M): q bf16
// ---------------------------------------------------------------------------
extern "C" void kernel_launch(void* const* d_in, const int* in_sizes, int n_in,
                              void* d_out, int out_size, void* d_ws, size_t ws_size,
                              hipStream_t stream) {
  const float* x  = (const float*)d_in[0];
  const float* Wq = (const float*)d_in[1];
  const float* Wk = (const float*)d_in[2];
  const float* Wv = (const float*)d_in[3];
  const float* Wo = (const float*)d_in[4];
  const float* qw = (const float*)d_in[5];
  const float* kw = (const float*)d_in[6];
  float* out = (float*)d_out;

  char* ws = (char*)d_ws;
  bf16* xb   = (bf16*)ws;
  bf16* WqT  = (bf16*)(ws + (16u << 20));
  bf16* WkvT = (bf16*)(ws + (16u << 20));
  bf16* kvb  = (bf16*)(ws + (32u << 20));
  float* cb  = (float*)(ws + (46u << 20));
  bf16* qb   = (bf16*)(ws + (48u << 20));
  bf16* attn = (bf16*)ws;
  bf16* WoT  = (bf16*)(ws + (16u << 20));

  // x -> bf16
  convert_kernel<<<(cT * cD) / (8 * 256), 256, 0, stream>>>(x, xb);
  // Wq^T bf16; q = xb * WqT^T (bf16 out)
  convT_kernel<<<dim3(cD / 64, cD / 64), 256, 0, stream>>>(Wq, WqT, cD, cD);
  gemm_bt_kernel<128, bf16><<<dim3(cD / 128, cT / 128), 256, 0, stream>>>(
      xb, WqT, qb, cT, cD, cD);
  // Wk^T|Wv^T bf16 (fused 2048x4096); kv = xb * WkvT^T (bf16 out)
  convT_kernel<<<dim3((cKV * cHD) / 64, cD / 64), 256, 0, stream>>>(Wk, WkvT, cD, cKV * cHD);
  convT_kernel<<<dim3((cKV * cHD) / 64, cD / 64), 256, 0, stream>>>(
      Wv, WkvT + (size_t)(cKV * cHD) * cD, cD, cKV * cHD);
  gemm_bt_kernel<64, bf16><<<dim3((2 * cKV * cHD) / 64, cT / 128), 256, 0, stream>>>(
      xb, WkvT, kvb, cT, 2 * cKV * cHD, cD);
  // rmsnorm + rope (in place, bf16); softmax shift bound
  norm_rope_kernel<<<(cT * (cH + cKV)) / 4, 256, 0, stream>>>(qb, kvb, qw, kw);
  bound_kernel<<<1, 64, 0, stream>>>(qw, kw, cb);
  // flash attention -> attn bf16 (reuses xb region)
  flash_kernel<<<dim3(cT / 128, cH), 256, 0, stream>>>(qb, kvb, cb, attn);
  // Wo^T bf16 (overwrites WkvT/kv region - both dead); out = attn * WoT^T (fp32)
  convT_kernel<<<dim3(cD / 64, cD / 64), 256, 0, stream>>>(Wo, WoT, cD, cD);
  gemm_bt_kernel<128, float><<<dim3(cD / 128, cT / 128), 256, 0, stream>>>(
      attn, WoT, out, cT, cD, cD);
}

// Round 5
// 556.439 us; speedup vs baseline: 1.0793x; 1.0793x over previous
//
#include <hip/hip_runtime.h>
#include <math.h>

typedef __bf16 bf16;
typedef __bf16 bf16x8 __attribute__((ext_vector_type(8)));
typedef float f32x4 __attribute__((ext_vector_type(4)));

constexpr int cT = 2048;
constexpr int cD = 4096;
constexpr int cH = 32;
constexpr int cKV = 8;
constexpr int cHD = 128;
constexpr float SCALE = 0.08838834764831845f; // 1/sqrt(128)

// Async global->LDS, 16B per lane. LDS dest must be WAVE-UNIFORM base;
// lane i's data lands at base + i*16 (guide §5 caveat).
__device__ __forceinline__ void gl_lds16(const bf16* g, bf16* l) {
  __builtin_amdgcn_global_load_lds(
      (const __attribute__((address_space(1))) unsigned*)g,
      (__attribute__((address_space(3))) unsigned*)l, 16, 0, 0);
}

__device__ inline bf16x8 load8_cvt(const float* __restrict__ p) {
  float4 a = *(const float4*)p;
  float4 b = *(const float4*)(p + 4);
  bf16x8 r;
  r[0] = (bf16)a.x; r[1] = (bf16)a.y; r[2] = (bf16)a.z; r[3] = (bf16)a.w;
  r[4] = (bf16)b.x; r[5] = (bf16)b.y; r[6] = (bf16)b.z; r[7] = (bf16)b.w;
  return r;
}

// ---------------------------------------------------------------------------
// fp32 -> bf16 elementwise (8 elems/thread)
// ---------------------------------------------------------------------------
__global__ __launch_bounds__(256) void convert_kernel(const float* __restrict__ s,
                                                      bf16* __restrict__ d) {
  const size_t i = (size_t)(blockIdx.x * 256 + threadIdx.x) * 8;
  *(bf16x8*)(d + i) = load8_cvt(s + i);
}

// ---------------------------------------------------------------------------
// Transpose + convert: dst[c][r] = (bf16)src[r][c]. src is R x C fp32,
// dst is C x R bf16 (row stride R). 64x64 LDS tile.
// ---------------------------------------------------------------------------
__global__ __launch_bounds__(256) void convT_kernel(const float* __restrict__ src,
                                                    bf16* __restrict__ dst,
                                                    int R, int C) {
  __shared__ float t[64][65];
  const int r0 = blockIdx.y * 64, c0 = blockIdx.x * 64;
  const int tid = threadIdx.x;
  {
    const int lr = tid >> 4, lc = (tid & 15) * 4;
#pragma unroll
    for (int i = 0; i < 4; ++i) {
      float4 v4 = *(const float4*)(src + (size_t)(r0 + lr + i * 16) * C + c0 + lc);
      t[lr + i * 16][lc] = v4.x;
      t[lr + i * 16][lc + 1] = v4.y;
      t[lr + i * 16][lc + 2] = v4.z;
      t[lr + i * 16][lc + 3] = v4.w;
    }
  }
  __syncthreads();
  {
    const int c = tid >> 2, rb = (tid & 3) * 16;
#pragma unroll
    for (int half = 0; half < 2; ++half) {
      bf16x8 o;
#pragma unroll
      for (int j = 0; j < 8; ++j) o[j] = (bf16)t[rb + half * 8 + j][c];
      *(bf16x8*)(dst + (size_t)(c0 + c) * R + r0 + rb + half * 8) = o;
    }
  }
}

// ---------------------------------------------------------------------------
// 8-wave m97-structure GEMM, R2 dbuf pipeline (counted-vmcnt ring of R4
// REVERTED: it regressed -16% -- VALUBusy 15.5->39, the asm waits pinned the
// scheduler; guide m131/m141 reproduced).
// C[M,N] = A[M,K] * BT[N,K]^T, both operands bf16 K-major. 128xBN block
// tile, BK=32, 512 threads (8 waves, 4x2), wave owns 32 x BN/2 output.
//
// Why 8 waves: grid is fixed at 512 blocks (M=2048) -> 2 blocks/CU. With
// 4-wave blocks that is 2 waves/SIMD -- too little TLP to hide the barrier
// drain (R2: MfmaUtil 28, VALUBusy 15, both pipes ~60% idle). 8-wave blocks
// at the same tile give 16 waves/CU = 4 waves/SIMD, same 32 KB LDS, lower
// VGPR (acc halves to 2xTN f32x4). LDS-BW cap at this fragment scheme
// (0.75 ds_read_b128 per MFMA) is ~1100 TF -- not limiting.
//
// Pipeline per K-slice: __syncthreads (drains own gl_lds via vmcnt(0)),
// issue next slice into buf^1, ds_read + MFMA on cur.
// ---------------------------------------------------------------------------
template <int BN, typename OutT>
__global__ __launch_bounds__(512) void gemm_bt_kernel(const bf16* __restrict__ A,
                                                      const bf16* __restrict__ BT,
                                                      OutT* __restrict__ C,
                                                      int M, int N, int K) {
  __shared__ __align__(16) bf16 As[2][128][32];
  __shared__ __align__(16) bf16 Bs[2][BN][32];
  constexpr int TN = BN / 32;  // n-tiles per wave

  const int tid = threadIdx.x;
  const int lane = tid & 63, w = tid >> 6;  // w = 0..7
  const int ln = lane & 15, kg = lane >> 4;
  const int m0 = blockIdx.y * 128, n0 = blockIdx.x * BN;
  const int wm = (w >> 1) * 32;        // 4 m-positions of 32 rows
  const int wn = (w & 1) * (BN / 2);   // 2 n-positions

  f32x4 acc[2][TN] = {};

  const int srow = lane >> 2;          // 0..15 within a 16-row chunk
  const int schk = (lane & 3) * 8;     // k-chunk (bf16 elems)
  const bf16* aG = A + (size_t)(m0 + srow) * K + schk;
  const bf16* bG = BT + (size_t)(n0 + srow) * K + schk;

  // Per-slice staging: wave w loads A rows [w*16, w*16+16); for B, the
  // first BN/16 waves load B rows [w*16, w*16+16). All wave-uniform.
  auto stage = [&](int kt, int db) {
    gl_lds16(aG + (size_t)(w * 16) * K + kt, &As[db][w * 16][0]);
    if (w < BN / 16)
      gl_lds16(bG + (size_t)(w * 16) * K + kt, &Bs[db][w * 16][0]);
  };

  stage(0, 0);

  for (int kt = 0; kt < K; kt += 32) {
    const int db = (kt >> 5) & 1;
    __syncthreads();  // drains this wave's gl_lds for tile kt (vmcnt(0))
    if (kt + 32 < K) stage(kt + 32, db ^ 1);

    bf16x8 af[2], bfr[TN];
#pragma unroll
    for (int tm = 0; tm < 2; ++tm)
      af[tm] = *(const bf16x8*)(&As[db][wm + tm * 16 + ln][kg * 8]);
#pragma unroll
    for (int tn = 0; tn < TN; ++tn)
      bfr[tn] = *(const bf16x8*)(&Bs[db][wn + tn * 16 + ln][kg * 8]);
#pragma unroll
    for (int tm = 0; tm < 2; ++tm)
#pragma unroll
      for (int tn = 0; tn < TN; ++tn)
        acc[tm][tn] = __builtin_amdgcn_mfma_f32_16x16x32_bf16(
            af[tm], bfr[tn], acc[tm][tn], 0, 0, 0);
  }

#pragma unroll
  for (int tm = 0; tm < 2; ++tm)
#pragma unroll
    for (int tn = 0; tn < TN; ++tn)
#pragma unroll
      for (int r = 0; r < 4; ++r)
        C[(size_t)(m0 + wm + tm * 16 + kg * 4 + r) * N + n0 + wn + tn * 16 + ln] =
            (OutT)acc[tm][tn][r];
}

// ---------------------------------------------------------------------------
// RMSNorm (per head, HD=128) + RoPE, in place on bf16 q and kv(k part).
// Q additionally pre-scaled by 1/sqrt(HD). One wave per (t, head).
// ---------------------------------------------------------------------------
__global__ __launch_bounds__(256) void norm_rope_kernel(bf16* __restrict__ q,
                                                        bf16* __restrict__ kv,
                                                        const float* __restrict__ qw,
                                                        const float* __restrict__ kw) {
  const int gw = (blockIdx.x * 256 + threadIdx.x) >> 6;
  const int lane = threadIdx.x & 63;
  bf16* base;
  const float* wgt;
  float post;
  int t;
  if (gw < cT * cH) {
    t = gw >> 5;
    int h = gw & 31;
    base = q + (size_t)t * (cH * cHD) + h * cHD;
    wgt = qw;
    post = SCALE;
  } else {
    int g2 = gw - cT * cH;
    t = g2 >> 3;
    int h = g2 & 7;
    base = kv + (size_t)t * (2 * cKV * cHD) + h * cHD;  // k part of kv buffer
    wgt = kw;
    post = 1.0f;
  }
  const int d0 = lane * 2;
  float x0 = (float)base[d0], x1 = (float)base[d0 + 1];
  float ss = x0 * x0 + x1 * x1;
#pragma unroll
  for (int off = 32; off > 0; off >>= 1) ss += __shfl_xor(ss, off, 64);
  const float rs = rsqrtf(ss * (1.0f / 128.0f) + 1e-6f);
  float y0 = x0 * rs * wgt[d0];
  float y1 = x1 * rs * wgt[d0 + 1];
  float p0 = __shfl_xor(y0, 32, 64);
  float p1 = __shfl_xor(y1, 32, 64);
  const float sgn = (lane < 32) ? -1.0f : 1.0f;  // first half gets -x2
  const int fi = d0 & 63;
  const float c1 = -19.93156856932417f / 64.0f;  // -log2(1e6)/64
  float inv0 = exp2f((float)fi * c1);
  float inv1 = exp2f((float)(fi + 1) * c1);
  float a0 = (float)t * inv0, a1 = (float)t * inv1;
  float o0 = (y0 * cosf(a0) + sgn * p0 * sinf(a0)) * post;
  float o1 = (y1 * cosf(a1) + sgn * p1 * sinf(a1)) * post;
  base[d0] = (bf16)o0;
  base[d0 + 1] = (bf16)o1;
}

// ---------------------------------------------------------------------------
// Score upper bound: S <= 128*SCALE*max|qw|*max|kw| (RMSNorm bounds row norms,
// RoPE is a rotation). Used as the fixed softmax shift C (shift-invariant).
// ---------------------------------------------------------------------------
__global__ void bound_kernel(const float* __restrict__ qw,
                             const float* __restrict__ kw,
                             float* __restrict__ cb) {
  const int lane = threadIdx.x;  // 64 threads
  float mq = fmaxf(fabsf(qw[lane]), fabsf(qw[lane + 64]));
  float mk = fmaxf(fabsf(kw[lane]), fabsf(kw[lane + 64]));
#pragma unroll
  for (int off = 32; off > 0; off >>= 1) {
    mq = fmaxf(mq, __shfl_xor(mq, off, 64));
    mk = fmaxf(mk, __shfl_xor(mk, off, 64));
  }
  if (lane == 0) *cb = 128.0f * SCALE * mq * mk + 1e-3f;
}

// ---------------------------------------------------------------------------
// MFMA flash attention (causal, GQA), fixed-C softmax (no per-tile cross-lane
// reductions, no rescaling). 128 Q rows per block, 4 waves, wave = 32 rows.
// Each Ks/VT B-frag read feeds 2 MFMAs (mt=0,1).
//
// Scheduling: LDS = 54272 B and grid = 512 -> exactly 2 resident blocks/CU,
// co-resident pair = (linear i, i+256) = same blockIdx.x. Map qt so the pair
// is work-complementary: every CU totals 36 tile-units (was 4..64 -> tail).
//
// Staging: T14 async split. K/V tile kt+1 global loads are issued right after
// the first barrier and land while tile kt computes; regs are written to LDS
// at the top of the next iteration (after the trailing barrier).
// ---------------------------------------------------------------------------
__global__ __launch_bounds__(256) void flash_kernel(const bf16* __restrict__ q,
                                                    const bf16* __restrict__ kv,
                                                    const float* __restrict__ cb,
                                                    bf16* __restrict__ out) {
  __shared__ bf16 Ks[64][136];
  __shared__ bf16 VT[128][72];
  __shared__ bf16 Ps[4][32][72];

  constexpr int KVS = 2 * cKV * cHD;  // 2048, kv row stride
  // Balanced complementary mapping (see header comment): covers every (qt,h)
  // exactly once: y<16 -> qt=15-x with h=y; y>=16 -> qt=x with h=y.
  const int qt = (blockIdx.y < 16) ? (15 - blockIdx.x) : blockIdx.x;
  const int h = blockIdx.y;
  const int qm0 = qt * 128;
  const int kh = h >> 2;  // kv head (G=4)
  const int tid = threadIdx.x;
  const int lane = tid & 63, w = tid >> 6;
  const int ln = lane & 15, kg = lane >> 4;
  const float C = *cb;
  const int row0 = qm0 + w * 32;  // wave's first Q row

  // --- preload Q A-frags: rows row0 + mt*16 + ln ---
  bf16x8 qa[2][4];
#pragma unroll
  for (int mt = 0; mt < 2; ++mt) {
    const bf16* qrow =
        q + (size_t)(row0 + mt * 16 + ln) * (cH * cHD) + h * cHD + kg * 8;
#pragma unroll
    for (int kk = 0; kk < 4; ++kk) qa[mt][kk] = *(const bf16x8*)(qrow + kk * 32);
  }

  const int sl = tid >> 2, sc = tid & 3;    // K staging: row sl, chunk sc*32
  const int vp = tid & 31, vc = tid >> 5;   // V staging: row-pair 2vp, chunk vc*16
  const bf16* kbase = kv + (size_t)sl * KVS + kh * cHD + sc * 32;
  const bf16* vbase = kv + cKV * cHD + (size_t)(2 * vp) * KVS + kh * cHD + vc * 16;

  float l_r[2][4] = {};
  f32x4 o_acc[2][8] = {};

  const int nkt = 2 * qt + 2;

  // ---- prologue: load tile 0 into staging regs ----
  bf16x8 kr[4], vr[4];
#pragma unroll
  for (int i = 0; i < 4; ++i) kr[i] = *(const bf16x8*)(kbase + i * 8);
  vr[0] = *(const bf16x8*)(vbase);
  vr[1] = *(const bf16x8*)(vbase + 8);
  vr[2] = *(const bf16x8*)(vbase + KVS);
  vr[3] = *(const bf16x8*)(vbase + KVS + 8);

  for (int kt = 0; kt < nkt; ++kt) {
    // ---- write staged K tile (loaded last iter / prologue) ----
#pragma unroll
    for (int i = 0; i < 4; ++i)
      *(bf16x8*)(&Ks[sl][sc * 32 + i * 8]) = kr[i];
    // ---- write staged V tile transposed (pair-packed b32 writes) ----
#pragma unroll
    for (int i = 0; i < 8; ++i) {
      union { bf16 hh[2]; unsigned u; } pk;
      pk.hh[0] = vr[0][i]; pk.hh[1] = vr[2][i];
      *(unsigned*)(&VT[vc * 16 + i][2 * vp]) = pk.u;
      pk.hh[0] = vr[1][i]; pk.hh[1] = vr[3][i];
      *(unsigned*)(&VT[vc * 16 + 8 + i][2 * vp]) = pk.u;
    }
    __syncthreads();

    // ---- issue next-tile global loads; they land under the compute below ----
    if (kt + 1 < nkt) {
      const bf16* kn = kbase + (size_t)(kt + 1) * 64 * KVS;
      const bf16* vn = vbase + (size_t)(kt + 1) * 64 * KVS;
#pragma unroll
      for (int i = 0; i < 4; ++i) kr[i] = *(const bf16x8*)(kn + i * 8);
      vr[0] = *(const bf16x8*)(vn);
      vr[1] = *(const bf16x8*)(vn + 8);
      vr[2] = *(const bf16x8*)(vn + KVS);
      vr[3] = *(const bf16x8*)(vn + KVS + 8);
    }

    // ---- S = Q K^T : B-frags shared across mt ----
    f32x4 s_acc[2][4] = {};
    __builtin_amdgcn_s_setprio(1);
#pragma unroll
    for (int kk = 0; kk < 4; ++kk)
#pragma unroll
      for (int nt = 0; nt < 4; ++nt) {
        bf16x8 bfr = *(const bf16x8*)(&Ks[nt * 16 + ln][kk * 32 + kg * 8]);
        s_acc[0][nt] = __builtin_amdgcn_mfma_f32_16x16x32_bf16(
            qa[0][kk], bfr, s_acc[0][nt], 0, 0, 0);
        s_acc[1][nt] = __builtin_amdgcn_mfma_f32_16x16x32_bf16(
            qa[1][kk], bfr, s_acc[1][nt], 0, 0, 0);
      }
    __builtin_amdgcn_s_setprio(0);

    // ---- P = exp(S - C) (masked on edge tiles), per-lane row sums ----
    const bool edge = (kt * 64 + 63 > row0);  // wave-uniform
#pragma unroll
    for (int mt = 0; mt < 2; ++mt)
#pragma unroll
      for (int nt = 0; nt < 4; ++nt)
#pragma unroll
        for (int r = 0; r < 4; ++r) {
          float pe = __expf(s_acc[mt][nt][r] - C);
          if (edge) {
            int col = kt * 64 + nt * 16 + ln;
            int row = row0 + mt * 16 + kg * 4 + r;
            if (col > row) pe = 0.f;
          }
          l_r[mt][r] += pe;
          Ps[w][mt * 16 + kg * 4 + r][nt * 16 + ln] = (bf16)pe;
        }

    // ---- O += P V (no rescale needed with fixed C) ----
    __builtin_amdgcn_s_setprio(1);
#pragma unroll
    for (int kk2 = 0; kk2 < 2; ++kk2) {
      bf16x8 pa0 = *(const bf16x8*)(&Ps[w][ln][kk2 * 32 + kg * 8]);
      bf16x8 pa1 = *(const bf16x8*)(&Ps[w][16 + ln][kk2 * 32 + kg * 8]);
#pragma unroll
      for (int dt = 0; dt < 8; ++dt) {
        bf16x8 vb = *(const bf16x8*)(&VT[dt * 16 + ln][kk2 * 32 + kg * 8]);
        o_acc[0][dt] = __builtin_amdgcn_mfma_f32_16x16x32_bf16(
            pa0, vb, o_acc[0][dt], 0, 0, 0);
        o_acc[1][dt] = __builtin_amdgcn_mfma_f32_16x16x32_bf16(
            pa1, vb, o_acc[1][dt], 0, 0, 0);
      }
    }
    __builtin_amdgcn_s_setprio(0);
    __syncthreads();
  }

  // ---- one final cross-lane reduction of l over ln (within kg group) ----
#pragma unroll
  for (int mt = 0; mt < 2; ++mt)
#pragma unroll
    for (int r = 0; r < 4; ++r) {
      float l = l_r[mt][r];
#pragma unroll
      for (int off = 1; off <= 8; off <<= 1) l += __shfl_xor(l, off, 64);
      l_r[mt][r] = 1.0f / l;
    }

  // ---- epilogue ----
#pragma unroll
  for (int mt = 0; mt < 2; ++mt) {
    bf16* op = out + (size_t)(row0 + mt * 16 + kg * 4) * (cH * cHD) + h * cHD + ln;
#pragma unroll
    for (int dt = 0; dt < 8; ++dt)
#pragma unroll
      for (int r = 0; r < 4; ++r)
        op[(size_t)r * (cH * cHD) + dt * 16] = (bf16)(o_acc[mt][dt][r] * l_r[mt][r]);
  }
}

// ---------------------------------------------------------------------------
// Workspace choreography (peak exactly 64 MiB, stream-ordered reuse):
//   [ 0,16M): xb (x bf16)            -> attn (after flash)
//   [16,48M): WqT (32M)              -> { WkvT [16,32M), kv [32,40M), Cb@46M }
//                                    -> WoT (after flash)
//   [48,64M): q bf16
// ---------------------------------------------------------------------------
extern "C" void kernel_launch(void* const* d_in, const int* in_sizes, int n_in,
                              void* d_out, int out_size, void* d_ws, size_t ws_size,
                              hipStream_t stream) {
  const float* x  = (const float*)d_in[0];
  const float* Wq = (const float*)d_in[1];
  const float* Wk = (const float*)d_in[2];
  const float* Wv = (const float*)d_in[3];
  const float* Wo = (const float*)d_in[4];
  const float* qw = (const float*)d_in[5];
  const float* kw = (const float*)d_in[6];
  float* out = (float*)d_out;

  char* ws = (char*)d_ws;
  bf16* xb   = (bf16*)ws;
  bf16* WqT  = (bf16*)(ws + (16u << 20));
  bf16* WkvT = (bf16*)(ws + (16u << 20));
  bf16* kvb  = (bf16*)(ws + (32u << 20));
  float* cb  = (float*)(ws + (46u << 20));
  bf16* qb   = (bf16*)(ws + (48u << 20));
  bf16* attn = (bf16*)ws;
  bf16* WoT  = (bf16*)(ws + (16u << 20));

  // x -> bf16
  convert_kernel<<<(cT * cD) / (8 * 256), 256, 0, stream>>>(x, xb);
  // Wq^T bf16; q = xb * WqT^T (bf16 out)
  convT_kernel<<<dim3(cD / 64, cD / 64), 256, 0, stream>>>(Wq, WqT, cD, cD);
  gemm_bt_kernel<128, bf16><<<dim3(cD / 128, cT / 128), 512, 0, stream>>>(
      xb, WqT, qb, cT, cD, cD);
  // Wk^T|Wv^T bf16 (fused 2048x4096); kv = xb * WkvT^T (bf16 out)
  convT_kernel<<<dim3((cKV * cHD) / 64, cD / 64), 256, 0, stream>>>(Wk, WkvT, cD, cKV * cHD);
  convT_kernel<<<dim3((cKV * cHD) / 64, cD / 64), 256, 0, stream>>>(
      Wv, WkvT + (size_t)(cKV * cHD) * cD, cD, cKV * cHD);
  gemm_bt_kernel<64, bf16><<<dim3((2 * cKV * cHD) / 64, cT / 128), 512, 0, stream>>>(
      xb, WkvT, kvb, cT, 2 * cKV * cHD, cD);
  // rmsnorm + rope (in place, bf16); softmax shift bound
  norm_rope_kernel<<<(cT * (cH + cKV)) / 4, 256, 0, stream>>>(qb, kvb, qw, kw);
  bound_kernel<<<1, 64, 0, stream>>>(qw, kw, cb);
  // flash attention -> attn bf16 (reuses xb region)
  flash_kernel<<<dim3(cT / 128, cH), 256, 0, stream>>>(qb, kvb, cb, attn);
  // Wo^T bf16 (overwrites WkvT/kv region - both dead); out = attn * WoT^T (fp32)
  convT_kernel<<<dim3(cD / 64, cD / 64), 256, 0, stream>>>(Wo, WoT, cD, cD);
  gemm_bt_kernel<128, float><<<dim3(cD / 128, cT / 128), 512, 0, stream>>>(
      attn, WoT, out, cT, cD, cD);
}